// Round 2
// baseline (389.275 us; speedup 1.0000x reference)
//
#include <hip/hip_runtime.h>
#include <hip/hip_bf16.h>

#define T_DIM 4096
#define B_DIM 16
#define C_DIM 512
#define H_DIM 128
#define M_DIM (T_DIM * B_DIM)   // 65536 rows

// ---------------- GEMM: v = sigmoid(x@Bw^T + Bb) * (x@Uw^T + Ub) ----------------
#define BM 128
#define BK 32
#define LDK 40   // padded LDS row stride (bf16 elems)

using floatx4 = __attribute__((ext_vector_type(4))) float;
using bf16x8  = __attribute__((ext_vector_type(8))) __bf16;

union bfpack { ushort4 u4; __hip_bfloat16 b[4]; };

__global__ __launch_bounds__(256, 2) void gemm_gates(
    const float* __restrict__ x, const float* __restrict__ Uw,
    const float* __restrict__ Ub, const float* __restrict__ Bw,
    const float* __restrict__ Bb, float* __restrict__ v)
{
    __shared__ __bf16 As[BM * LDK];
    __shared__ __bf16 Ws[256 * LDK];   // rows 0..127 = Uw, 128..255 = Bw

    const int tid  = threadIdx.x;
    const int wid  = tid >> 6;
    const int lane = tid & 63;
    const int m0   = blockIdx.x * BM;

    const int wm = (wid >> 1) * 64;
    const int wn = (wid & 1) * 64;
    const int row = lane & 15;
    const int q   = lane >> 4;

    floatx4 acc_u[4][4], acc_b[4][4];
    const floatx4 fzero = {0.f, 0.f, 0.f, 0.f};
#pragma unroll
    for (int mt = 0; mt < 4; ++mt)
#pragma unroll
        for (int nt = 0; nt < 4; ++nt) { acc_u[mt][nt] = fzero; acc_b[mt][nt] = fzero; }

    for (int ks = 0; ks < C_DIM / BK; ++ks) {
        const int k0 = ks * BK;
        __syncthreads();
#pragma unroll
        for (int it = 0; it < 4; ++it) {
            int idx = tid + it * 256;
            int r = idx >> 3, c4 = (idx & 7) * 4;
            const float4 f = *(const float4*)(x + (size_t)(m0 + r) * C_DIM + k0 + c4);
            bfpack pk;
            pk.b[0] = __float2bfloat16(f.x); pk.b[1] = __float2bfloat16(f.y);
            pk.b[2] = __float2bfloat16(f.z); pk.b[3] = __float2bfloat16(f.w);
            *(ushort4*)&As[r * LDK + c4] = pk.u4;
        }
#pragma unroll
        for (int it = 0; it < 8; ++it) {
            int idx = tid + it * 256;
            int r = idx >> 3, c4 = (idx & 7) * 4;
            const float* src = (r < 128) ? (Uw + (size_t)r * C_DIM)
                                         : (Bw + (size_t)(r - 128) * C_DIM);
            const float4 f = *(const float4*)(src + k0 + c4);
            bfpack pk;
            pk.b[0] = __float2bfloat16(f.x); pk.b[1] = __float2bfloat16(f.y);
            pk.b[2] = __float2bfloat16(f.z); pk.b[3] = __float2bfloat16(f.w);
            *(ushort4*)&Ws[r * LDK + c4] = pk.u4;
        }
        __syncthreads();

        bf16x8 afr[4], ufr[4], bfr[4];
#pragma unroll
        for (int mt = 0; mt < 4; ++mt)
            afr[mt] = *(const bf16x8*)&As[(wm + mt * 16 + row) * LDK + q * 8];
#pragma unroll
        for (int nt = 0; nt < 4; ++nt) {
            ufr[nt] = *(const bf16x8*)&Ws[(wn + nt * 16 + row) * LDK + q * 8];
            bfr[nt] = *(const bf16x8*)&Ws[(128 + wn + nt * 16 + row) * LDK + q * 8];
        }
#pragma unroll
        for (int mt = 0; mt < 4; ++mt)
#pragma unroll
            for (int nt = 0; nt < 4; ++nt) {
                acc_u[mt][nt] = __builtin_amdgcn_mfma_f32_16x16x32_bf16(
                    afr[mt], ufr[nt], acc_u[mt][nt], 0, 0, 0);
                acc_b[mt][nt] = __builtin_amdgcn_mfma_f32_16x16x32_bf16(
                    afr[mt], bfr[nt], acc_b[mt][nt], 0, 0, 0);
            }
    }

#pragma unroll
    for (int nt = 0; nt < 4; ++nt) {
        const int h = wn + nt * 16 + row;
        const float ub = Ub[h], bb = Bb[h];
#pragma unroll
        for (int mt = 0; mt < 4; ++mt) {
#pragma unroll
            for (int r = 0; r < 4; ++r) {
                const int m = m0 + wm + mt * 16 + q * 4 + r;
                const float uu = acc_u[mt][nt][r] + ub;
                const float gg = acc_b[mt][nt][r] + bb;
                v[(size_t)m * H_DIM + h] = uu / (1.f + __expf(-gg));
            }
        }
    }
}

// ---------------- Recurrence: wave-per-chain, zero barriers ----------------
// One 64-lane wave owns one (chunk, b) chain. Lane l owns rows l and l+64:
// A rows in 256 VGPRs, h broadcast through per-wave LDS (intra-wave ordering
// only needs lgkmcnt -> no s_barrier). v prefetched 2 steps ahead.
// 64 chunks x 16 batches = 1024 wave-chains = 256 blocks x 256 threads.

#define CHUNK_L 64
#define WARM_K  32

__global__ __launch_bounds__(256, 1) void recur_kernel(
    const float* __restrict__ v, const float* __restrict__ A,
    float* __restrict__ out)
{
    const int tid  = threadIdx.x;
    const int wid  = tid >> 6;
    const int lane = tid & 63;
    const int cid   = blockIdx.x * 4 + wid;   // 0..1023
    const int chunk = cid >> 4;               // 0..63
    const int b     = cid & 15;
    const int r0    = lane;
    const int r1    = lane + 64;

    __shared__ float hs[4][H_DIM];
    float* h = hs[wid];

    // A rows -> registers
    float a0[H_DIM], a1[H_DIM];
    {
        const float4* A0 = (const float4*)(A + (size_t)r0 * H_DIM);
        const float4* A1 = (const float4*)(A + (size_t)r1 * H_DIM);
#pragma unroll
        for (int jj = 0; jj < 32; ++jj) {
            float4 f0 = A0[jj], f1 = A1[jj];
            a0[4*jj+0] = f0.x; a0[4*jj+1] = f0.y; a0[4*jj+2] = f0.z; a0[4*jj+3] = f0.w;
            a1[4*jj+0] = f1.x; a1[4*jj+1] = f1.y; a1[4*jj+2] = f1.z; a1[4*jj+3] = f1.w;
        }
    }

    h[r0] = 0.f;
    h[r1] = 0.f;

    const int tout = chunk * CHUNK_L;
    const int ts   = (tout - WARM_K < 0) ? 0 : tout - WARM_K;
    const int tend = tout + CHUNK_L;

    // rotating 2-deep prefetch of v
    float pv0[2], pv1[2];
    {
        const size_t base0 = (size_t)(ts * B_DIM + b) * H_DIM;
        const size_t base1 = (size_t)((ts + 1) * B_DIM + b) * H_DIM;
        pv0[0] = v[base0 + r0]; pv1[0] = v[base0 + r1];
        pv0[1] = v[base1 + r0]; pv1[1] = v[base1 + r1];
    }

#pragma unroll 2
    for (int t = ts; t < tend; ++t) {
        const int slot = t & 1;
        const float cur0 = pv0[slot];
        const float cur1 = pv1[slot];
        // prefetch t+2 (overwrites the slot just consumed)
        if (t + 2 < tend) {
            const size_t basep = (size_t)((t + 2) * B_DIM + b) * H_DIM;
            pv0[slot] = v[basep + r0];
            pv1[slot] = v[basep + r1];
        }

        float s00 = cur0, s01 = 0.f, s02 = 0.f, s03 = 0.f;
        float s10 = cur1, s11 = 0.f, s12 = 0.f, s13 = 0.f;
        const float4* h4 = (const float4*)h;
#pragma unroll
        for (int jj = 0; jj < 32; ++jj) {
            const float4 hv = h4[jj];
            s00 += a0[4*jj+0] * hv.x; s01 += a0[4*jj+1] * hv.y;
            s02 += a0[4*jj+2] * hv.z; s03 += a0[4*jj+3] * hv.w;
            s10 += a1[4*jj+0] * hv.x; s11 += a1[4*jj+1] * hv.y;
            s12 += a1[4*jj+2] * hv.z; s13 += a1[4*jj+3] * hv.w;
        }
        const float hn0 = (s00 + s01) + (s02 + s03);
        const float hn1 = (s10 + s11) + (s12 + s13);

        // intra-wave: lockstep write then read, compiler inserts lgkmcnt wait
        h[r0] = hn0;
        h[r1] = hn1;

        if (t >= tout) {
            const size_t ob = (size_t)(t * B_DIM + b) * H_DIM;
            out[ob + r0] = hn0;
            out[ob + r1] = hn1;
        }
    }
}

// ------------------------------------------------------------------------------

extern "C" void kernel_launch(void* const* d_in, const int* in_sizes, int n_in,
                              void* d_out, int out_size, void* d_ws, size_t ws_size,
                              hipStream_t stream) {
    const float* x  = (const float*)d_in[0];
    const float* Uw = (const float*)d_in[1];
    const float* Ub = (const float*)d_in[2];
    const float* Bw = (const float*)d_in[3];
    const float* Bb = (const float*)d_in[4];
    const float* Aw = (const float*)d_in[5];
    float* out = (float*)d_out;
    float* vbuf = (float*)d_ws;   // T*B*H fp32 = 32 MiB

    gemm_gates<<<M_DIM / BM, 256, 0, stream>>>(x, Uw, Ub, Bw, Bb, vbuf);
    recur_kernel<<<(T_DIM / CHUNK_L) * B_DIM / 4, 256, 0, stream>>>(vbuf, Aw, out);
}